// Round 3
// baseline (190.861 us; speedup 1.0000x reference)
//
#include <hip/hip_runtime.h>
#include <float.h>
#include <math.h>

#define B_SZ   2048
#define D_DIM  256
#define P_DIM  4
#define N_TOT  4096        // 2*B
#define EPS_F  1e-8f
#define NB     2560        // 512*5: stride-5 scan ownership (odd -> conflict-free)
#define BSCALE 640.0f      // tie-approx error ~5e-3 << 0.146 threshold

typedef short  s16x8 __attribute__((ext_vector_type(8)));
typedef float  f32x4 __attribute__((ext_vector_type(4)));

__device__ __forceinline__ void async_load16(const void* g, const void* l) {
    __builtin_amdgcn_global_load_lds(
        (const __attribute__((address_space(1))) unsigned int*)g,
        (__attribute__((address_space(3))) unsigned int*)l,
        16, 0, 0);
}

__device__ __forceinline__ unsigned short f2bf(float x) {
    unsigned int b = __float_as_uint(x);
    b += 0x7FFFu + ((b >> 16) & 1u);        // RNE
    return (unsigned short)(b >> 16);
}

// ---------------- Kernel A: row-normalize features -> bf16 ----------------
__global__ __launch_bounds__(64) void normalize_kernel(
    const float* __restrict__ z_i, const float* __restrict__ z_j,
    unsigned short* __restrict__ fb)
{
    int row  = blockIdx.x;
    int lane = threadIdx.x;
    const float* src = (row < B_SZ) ? (z_i + (size_t)row * D_DIM)
                                    : (z_j + (size_t)(row - B_SZ) * D_DIM);
    float4 v = ((const float4*)src)[lane];
    float ss = v.x*v.x + v.y*v.y + v.z*v.z + v.w*v.w;
    #pragma unroll
    for (int off = 32; off > 0; off >>= 1)
        ss += __shfl_down(ss, off, 64);
    ss = __shfl(ss, 0, 64);
    float inv = 1.0f / sqrtf(ss);
    ushort4 o;
    o.x = f2bf(v.x * inv); o.y = f2bf(v.y * inv);
    o.z = f2bf(v.z * inv); o.w = f2bf(v.w * inv);
    ((ushort4*)(fb + (size_t)row * D_DIM))[lane] = o;
}

// ---------------- Kernel B: logits = f @ f^T / TEMP, bf16 MFMA, 128x128 tile ----------------
// SPILL FIX: acc(64 VGPR) + frags(32) + addressing ~= 130 regs. Every prior round's
// __launch_bounds__(..., 4) capped VGPR at 128 -> accumulators spilled to scratch in
// the inner loop (invariant ~70us across 3 structural rewrites). No min-wave force:
// compiler picks ~150-170 VGPR, 3 blocks/CU, zero spill.
__global__ __launch_bounds__(256) void gemm_kernel(
    const unsigned short* __restrict__ fb, unsigned short* __restrict__ out)
{
    __shared__ unsigned short AB[2][256 * 32];   // 2 x 16 KB; rows [0,128)=A, [128,256)=B

    int tid = threadIdx.x;
    int w   = tid >> 6;           // 4 waves
    int L   = tid & 63;
    int bm  = blockIdx.y * 128;
    int bn  = blockIdx.x * 128;

    f32x4 acc[4][4];
    #pragma unroll
    for (int r = 0; r < 4; ++r)
        #pragma unroll
        for (int c = 0; c < 4; ++c)
            #pragma unroll
            for (int q = 0; q < 4; ++q) acc[r][c][q] = 0.f;

    const int wr = (w >> 1) * 64;      // wave quadrant: 2x2 grid of 64x64
    const int wc = (w & 1) * 64;

    // staging: wave w covers combined rows [w*64, w*64+64); k-chunk XOR swizzle on
    // the GLOBAL SOURCE side (global_load_lds writes linearly), swizzled read below.
    const int r_sub   = (L >> 2);
    const int k_src   = ((L & 3) ^ (r_sub & 3)) * 8;   // shorts

    #define STAGE(buf, k0)                                                        \
        {                                                                         \
            unsigned short* lb = AB[buf] + (w * 64) * 32;                         \
            _Pragma("unroll")                                                     \
            for (int c = 0; c < 4; ++c) {                                         \
                int r = w * 64 + c * 16 + r_sub;                                  \
                int grow = (r < 128) ? (bm + r) : (bn + r - 128);                 \
                async_load16(fb + (size_t)grow * D_DIM + (k0) + k_src,            \
                             lb + c * 512);                                       \
            }                                                                     \
        }

    STAGE(0, 0)
    __syncthreads();

    // fragment read: k-chunk (L>>4) of row R lives at slot (L>>4)^(R&3); R&3 == L&3
    // for all fragment rows (wr, rt*16, wc, ct*16 all multiples of 4).
    const int rslot = ((L >> 4) ^ (L & 3)) * 8;        // shorts

    int cur = 0;
    for (int k0 = 0; k0 < D_DIM; k0 += 32) {
        if (k0 + 32 < D_DIM) STAGE(cur ^ 1, k0 + 32)

        const unsigned short* buf = AB[cur];
        s16x8 a[4], b[4];
        #pragma unroll
        for (int rt = 0; rt < 4; ++rt)
            a[rt] = *(const s16x8*)(buf + (wr + rt * 16 + (L & 15)) * 32 + rslot);
        #pragma unroll
        for (int ct = 0; ct < 4; ++ct)
            b[ct] = *(const s16x8*)(buf + (128 + wc + ct * 16 + (L & 15)) * 32 + rslot);
        #pragma unroll
        for (int rt = 0; rt < 4; ++rt)
            #pragma unroll
            for (int ct = 0; ct < 4; ++ct)
                acc[rt][ct] = __builtin_amdgcn_mfma_f32_16x16x32_bf16(
                    a[rt], b[ct], acc[rt][ct], 0, 0, 0);

        __syncthreads();   // next buffer staged; cur buffer free
        cur ^= 1;
    }

    #pragma unroll
    for (int rt = 0; rt < 4; ++rt) {
        #pragma unroll
        for (int ct = 0; ct < 4; ++ct) {
            int col = bn + wc + ct * 16 + (L & 15);
            #pragma unroll
            for (int q = 0; q < 4; ++q) {
                int row = bm + wr + rt * 16 + (L >> 4) * 4 + q;
                out[(size_t)row * N_TOT + col] = f2bf(acc[rt][ct][q] * 0.5f); // /TEMP
            }
        }
    }
}

// ---------------- Kernel C: 1 row/block bucket-CDF (tie-approx) ----------------
// Latency restructure: 1 row per block, 512 threads, only 8 j's per thread.
// All phase-1 loads explicitly batched into registers (8 x float4 + 8 logits)
// -> one VMEM latency exposure instead of a 16-deep serial chain. Strided j
// (j = tid + 512t) keeps physics float4 and bf16 logit loads fully coalesced.
// No forced min-waves (R1 lesson: forcing occupancy caused scratch spill).
__global__ __launch_bounds__(512) void row_kernel(
    const unsigned short* __restrict__ logits,
    const float* __restrict__ physics_i, const float* __restrict__ physics_j,
    float* __restrict__ rowres)
{
    __shared__ float bs[NB];                 // 10240 B
    __shared__ float scr[24];                // [0..7] scan, [8..15] sl, [16..23] ls

    int tid  = threadIdx.x;
    int lane = tid & 63;
    int wid  = tid >> 6;                     // 0..7
    int i    = blockIdx.x;

    #pragma unroll
    for (int t = 0; t < NB / 512; ++t)       // 5 iters, lane-stride-1: conflict-free
        bs[tid + t * 512] = 0.f;

    const float* Lp = (i < B_SZ) ? (physics_i + (size_t)i * P_DIM)
                                 : (physics_j + (size_t)(i - B_SZ) * P_DIM);
    float4 Li = *(const float4*)Lp;
    __syncthreads();                                   // B0: zeros visible

    const unsigned short* lrow = logits + (size_t)i * N_TOT;

    // phase 1a: batched coalesced loads (independent, all in flight together)
    float4 Lj[8];
    float  lg[8];
    #pragma unroll
    for (int t = 0; t < 8; ++t) {
        int j = tid + t * 512;
        const float* p = (j < B_SZ) ? (physics_i + (size_t)j * P_DIM)
                                    : (physics_j + (size_t)(j - B_SZ) * P_DIM);
        Lj[t] = *(const float4*)p;
        lg[t] = __uint_as_float((unsigned)lrow[j] << 16);
    }

    // phase 1b: bucket + exp + histogram
    int pb[8];
    float sl = 0.f;
    #pragma unroll
    for (int t = 0; t < 8; ++t) {
        int j = tid + t * 512;
        float d = fabsf(Li.x - Lj[t].x) + fabsf(Li.y - Lj[t].y)
                + fabsf(Li.z - Lj[t].z) + fabsf(Li.w - Lj[t].w);
        int b = (int)(d * BSCALE); if (b > NB - 1) b = NB - 1;
        pb[t] = b;
        float e;
        if (j == i) e = 0.f; else { e = __expf(lg[t]); sl += lg[t]; }
        atomicAdd(&bs[b], e);
    }
    #pragma unroll
    for (int off = 32; off > 0; off >>= 1)
        sl += __shfl_down(sl, off, 64);
    if (lane == 0) scr[8 + wid] = sl;
    __syncthreads();                                   // B1: hist + row-logit sums

    // phase 2: inclusive suffix scan; thread owns [tid*5, tid*5+5)
    const int base = tid * 5;                          // stride 5: conflict-free
    float v[5];
    float fs = 0.f;
    #pragma unroll
    for (int k = 0; k < 5; ++k) { v[k] = bs[base + k]; fs += v[k]; }
    float s = fs;
    #pragma unroll
    for (int off = 1; off < 64; off <<= 1) {           // intra-wave suffix scan
        float u = __shfl_down(s, off, 64);
        if (lane + off < 64) s += u;
    }
    if (lane == 0) scr[wid] = s;                       // wave total
    __syncthreads();                                   // B2
    float sb = 0.f;
    for (int w = wid + 1; w < 8; ++w) sb += scr[w];
    float run = sb + s - fs;
    #pragma unroll
    for (int k = 4; k >= 0; --k) { run += v[k]; bs[base + k] = run; }
    __syncthreads();                                   // B3: suffix CDF ready

    // phase 3: denom lookups + logs
    float ls = 0.f;
    #pragma unroll
    for (int t = 0; t < 8; ++t) {
        int j = tid + t * 512;
        float dnm = bs[pb[t]];
        if (j != i) ls += __logf(dnm + EPS_F);
    }
    #pragma unroll
    for (int off = 32; off > 0; off >>= 1)
        ls += __shfl_down(ls, off, 64);
    if (lane == 0) scr[16 + wid] = ls;
    __syncthreads();                                   // B4
    if (tid == 0) {
        float lsum = 0.f, slo = 0.f;
        #pragma unroll
        for (int w = 0; w < 8; ++w) { lsum += scr[16 + w]; slo += scr[8 + w]; }
        rowres[i] = lsum - slo;
    }
}

// ---------------- Kernel D: final reduce ----------------
__global__ __launch_bounds__(256) void final_kernel(
    const float* __restrict__ rowres, float* __restrict__ out)
{
    __shared__ float red[4];
    int tid = threadIdx.x;
    float s = 0.f;
    for (int i = tid; i < N_TOT; i += 256) s += rowres[i];
    #pragma unroll
    for (int off = 32; off > 0; off >>= 1)
        s += __shfl_down(s, off, 64);
    if ((tid & 63) == 0) red[tid >> 6] = s;
    __syncthreads();
    if (tid == 0) {
        double tot = (double)red[0] + red[1] + red[2] + red[3];
        out[0] = (float)(tot / ((double)N_TOT * (N_TOT - 1)));
    }
}

extern "C" void kernel_launch(void* const* d_in, const int* in_sizes, int n_in,
                              void* d_out, int out_size, void* d_ws, size_t ws_size,
                              hipStream_t stream)
{
    const float* z_i  = (const float*)d_in[0];
    const float* z_j  = (const float*)d_in[1];
    const float* ph_i = (const float*)d_in[2];
    const float* ph_j = (const float*)d_in[3];

    unsigned short* fb     = (unsigned short*)d_ws;                        // 2 MB bf16
    unsigned short* logits = fb + (size_t)N_TOT * D_DIM;                   // 32 MB bf16
    float*          rowres = (float*)(logits + (size_t)N_TOT * N_TOT);     // 16 KB

    normalize_kernel<<<N_TOT, 64, 0, stream>>>(z_i, z_j, fb);
    dim3 g(N_TOT / 128, N_TOT / 128);
    gemm_kernel<<<g, 256, 0, stream>>>(fb, logits);
    row_kernel<<<N_TOT, 512, 0, stream>>>(logits, ph_i, ph_j, rowres);
    final_kernel<<<1, 256, 0, stream>>>(rowres, (float*)d_out);
}

// Round 4
// 181.129 us; speedup vs baseline: 1.0537x; 1.0537x over previous
//
#include <hip/hip_runtime.h>
#include <float.h>
#include <math.h>

#define B_SZ   2048
#define D_DIM  256
#define P_DIM  4
#define N_TOT  4096        // 2*B
#define EPS_F  1e-8f
#define NB     2304        // 256*9: stride-9 scan ownership is bank-conflict-free
#define BSCALE 576.0f      // tie-approx error ~6e-3 << 0.146 threshold

typedef short  s16x8 __attribute__((ext_vector_type(8)));
typedef float  f32x4 __attribute__((ext_vector_type(4)));

__device__ __forceinline__ void async_load16(const void* g, const void* l) {
    __builtin_amdgcn_global_load_lds(
        (const __attribute__((address_space(1))) unsigned int*)g,
        (__attribute__((address_space(3))) unsigned int*)l,
        16, 0, 0);
}

__device__ __forceinline__ unsigned short f2bf(float x) {
    unsigned int b = __float_as_uint(x);
    b += 0x7FFFu + ((b >> 16) & 1u);        // RNE
    return (unsigned short)(b >> 16);
}

// ---------------- Kernel A: row-normalize features -> bf16 ----------------
__global__ __launch_bounds__(64) void normalize_kernel(
    const float* __restrict__ z_i, const float* __restrict__ z_j,
    unsigned short* __restrict__ fb)
{
    int row  = blockIdx.x;
    int lane = threadIdx.x;
    const float* src = (row < B_SZ) ? (z_i + (size_t)row * D_DIM)
                                    : (z_j + (size_t)(row - B_SZ) * D_DIM);
    float4 v = ((const float4*)src)[lane];
    float ss = v.x*v.x + v.y*v.y + v.z*v.z + v.w*v.w;
    #pragma unroll
    for (int off = 32; off > 0; off >>= 1)
        ss += __shfl_down(ss, off, 64);
    ss = __shfl(ss, 0, 64);
    float inv = 1.0f / sqrtf(ss);
    ushort4 o;
    o.x = f2bf(v.x * inv); o.y = f2bf(v.y * inv);
    o.z = f2bf(v.z * inv); o.w = f2bf(v.w * inv);
    ((ushort4*)(fb + (size_t)row * D_DIM))[lane] = o;
}

// ---------------- Kernel B: logits = f @ f^T / TEMP, bf16 MFMA, 128x128 tile ----------------
// REGISTER BUDGET: acc 4x4xf32x4 = 64 VGPR + frags 32 + addressing ~= 130.
// R0-R2 capped VGPR at 128 (launch_bounds min-waves) -> accumulator spill;
// R3 (no bound) let the heuristic go low-VGPR (row_kernel showed VGPR=20!).
// (256, 1) brackets it: up to 256 VGPR allowed, no spill, ~3 blocks/CU.
__global__ __launch_bounds__(256, 1) void gemm_kernel(
    const unsigned short* __restrict__ fb, unsigned short* __restrict__ out)
{
    __shared__ unsigned short AB[2][256 * 32];   // 2 x 16 KB; rows [0,128)=A, [128,256)=B

    int tid = threadIdx.x;
    int w   = tid >> 6;           // 4 waves
    int L   = tid & 63;
    int bm  = blockIdx.y * 128;
    int bn  = blockIdx.x * 128;

    f32x4 acc[4][4];
    #pragma unroll
    for (int r = 0; r < 4; ++r)
        #pragma unroll
        for (int c = 0; c < 4; ++c)
            #pragma unroll
            for (int q = 0; q < 4; ++q) acc[r][c][q] = 0.f;

    const int wr = (w >> 1) * 64;      // wave quadrant: 2x2 grid of 64x64
    const int wc = (w & 1) * 64;

    // staging: wave w covers combined rows [w*64, w*64+64); k-chunk XOR swizzle on
    // the GLOBAL SOURCE side (global_load_lds writes linearly), swizzled read below.
    const int r_sub   = (L >> 2);
    const int k_src   = ((L & 3) ^ (r_sub & 3)) * 8;   // shorts

    #define STAGE(buf, k0)                                                        \
        {                                                                         \
            unsigned short* lb = AB[buf] + (w * 64) * 32;                         \
            _Pragma("unroll")                                                     \
            for (int c = 0; c < 4; ++c) {                                         \
                int r = w * 64 + c * 16 + r_sub;                                  \
                int grow = (r < 128) ? (bm + r) : (bn + r - 128);                 \
                async_load16(fb + (size_t)grow * D_DIM + (k0) + k_src,            \
                             lb + c * 512);                                       \
            }                                                                     \
        }

    STAGE(0, 0)
    __syncthreads();

    // fragment read: k-chunk (L>>4) of row R lives at slot (L>>4)^(R&3); R&3 == L&3
    // for all fragment rows (wr, rt*16, wc, ct*16 all multiples of 4).
    const int rslot = ((L >> 4) ^ (L & 3)) * 8;        // shorts

    int cur = 0;
    for (int k0 = 0; k0 < D_DIM; k0 += 32) {
        if (k0 + 32 < D_DIM) STAGE(cur ^ 1, k0 + 32)

        const unsigned short* buf = AB[cur];
        s16x8 a[4], b[4];
        #pragma unroll
        for (int rt = 0; rt < 4; ++rt)
            a[rt] = *(const s16x8*)(buf + (wr + rt * 16 + (L & 15)) * 32 + rslot);
        #pragma unroll
        for (int ct = 0; ct < 4; ++ct)
            b[ct] = *(const s16x8*)(buf + (128 + wc + ct * 16 + (L & 15)) * 32 + rslot);
        #pragma unroll
        for (int rt = 0; rt < 4; ++rt)
            #pragma unroll
            for (int ct = 0; ct < 4; ++ct)
                acc[rt][ct] = __builtin_amdgcn_mfma_f32_16x16x32_bf16(
                    a[rt], b[ct], acc[rt][ct], 0, 0, 0);

        __syncthreads();   // next buffer staged; cur buffer free
        cur ^= 1;
    }

    #pragma unroll
    for (int rt = 0; rt < 4; ++rt) {
        #pragma unroll
        for (int ct = 0; ct < 4; ++ct) {
            int col = bn + wc + ct * 16 + (L & 15);
            #pragma unroll
            for (int q = 0; q < 4; ++q) {
                int row = bm + wr + rt * 16 + (L >> 4) * 4 + q;
                out[(size_t)row * N_TOT + col] = f2bf(acc[rt][ct][q] * 0.5f); // /TEMP
            }
        }
    }
}

// ---------------- Kernel C: 2 rows/block fine-bucket CDF (tie-approx) ----------------
// Best-measured structure (R2: 98us). Only change: launch_bounds (256,4)->(256,2).
// R1 (min 8 waves) capped VGPR=32 -> spill; R3 (no bound) -> heuristic VGPR=20,
// loads serialized. (256,2) caps at 128: room for ~70 live regs, still 2 blocks/CU min.
__global__ __launch_bounds__(256, 2) void row_kernel(
    const unsigned short* __restrict__ logits,
    const float* __restrict__ physics_i, const float* __restrict__ physics_j,
    float* __restrict__ rowres)
{
    __shared__ float bs0[NB];                // 9216 B
    __shared__ float bs1[NB];                // 9216 B
    __shared__ float scr[24];

    int tid  = threadIdx.x;
    int lane = tid & 63;
    int wid  = tid >> 6;
    int i0   = blockIdx.x * 2;
    int i1   = i0 + 1;

    #pragma unroll
    for (int t = 0; t < NB / 256; ++t) {     // 9 iters, lane-stride-1: conflict-free
        bs0[tid + t * 256] = 0.f;
        bs1[tid + t * 256] = 0.f;
    }

    const float* Lp0 = (i0 < B_SZ) ? (physics_i + (size_t)i0 * P_DIM)
                                   : (physics_j + (size_t)(i0 - B_SZ) * P_DIM);
    const float* Lp1 = (i1 < B_SZ) ? (physics_i + (size_t)i1 * P_DIM)
                                   : (physics_j + (size_t)(i1 - B_SZ) * P_DIM);
    float4 Li0 = *(const float4*)Lp0;
    float4 Li1 = *(const float4*)Lp1;
    __syncthreads();                                   // B0: zeros visible

    const unsigned short* l0p = logits + (size_t)i0 * N_TOT;
    const unsigned short* l1p = logits + (size_t)i1 * N_TOT;

    // phase 1: coalesced gather, dual histogram
    unsigned pb[16];                                   // packed buckets b0 | b1<<16
    float sl0 = 0.f, sl1 = 0.f;
    #pragma unroll
    for (int t = 0; t < 16; ++t) {
        int j = tid + t * 256;                         // lane-consecutive: coalesced
        const float* p = (j < B_SZ) ? (physics_i + (size_t)j * P_DIM)
                                    : (physics_j + (size_t)(j - B_SZ) * P_DIM);
        float4 Lj = *(const float4*)p;
        float l0 = __uint_as_float((unsigned)l0p[j] << 16);
        float l1 = __uint_as_float((unsigned)l1p[j] << 16);
        float d0 = fabsf(Li0.x - Lj.x) + fabsf(Li0.y - Lj.y)
                 + fabsf(Li0.z - Lj.z) + fabsf(Li0.w - Lj.w);
        float d1 = fabsf(Li1.x - Lj.x) + fabsf(Li1.y - Lj.y)
                 + fabsf(Li1.z - Lj.z) + fabsf(Li1.w - Lj.w);
        int b0 = (int)(d0 * BSCALE); if (b0 > NB - 1) b0 = NB - 1;
        int b1 = (int)(d1 * BSCALE); if (b1 > NB - 1) b1 = NB - 1;
        pb[t] = (unsigned)b0 | ((unsigned)b1 << 16);
        float e0, e1;
        if (j == i0) e0 = 0.f; else { e0 = __expf(l0); sl0 += l0; }
        if (j == i1) e1 = 0.f; else { e1 = __expf(l1); sl1 += l1; }
        atomicAdd(&bs0[b0], e0);
        atomicAdd(&bs1[b1], e1);
    }
    #pragma unroll
    for (int off = 32; off > 0; off >>= 1) {
        sl0 += __shfl_down(sl0, off, 64);
        sl1 += __shfl_down(sl1, off, 64);
    }
    if (lane == 0) { scr[8 + wid] = sl0; scr[12 + wid] = sl1; }
    __syncthreads();                                   // B1: hist + sums ready
    float slo0 = scr[8]  + scr[9]  + scr[10] + scr[11];
    float slo1 = scr[12] + scr[13] + scr[14] + scr[15];

    // phase 2: dual inclusive suffix scan; thread owns [tid*9, tid*9+9)
    const int base = tid * 9;                          // stride 9: conflict-free
    float v0[9], v1[9];
    float fs0 = 0.f, fs1 = 0.f;
    #pragma unroll
    for (int k = 0; k < 9; ++k) {
        v0[k] = bs0[base + k]; fs0 += v0[k];
        v1[k] = bs1[base + k]; fs1 += v1[k];
    }
    float s0 = fs0, s1 = fs1;
    #pragma unroll
    for (int off = 1; off < 64; off <<= 1) {
        float u0 = __shfl_down(s0, off, 64);
        float u1 = __shfl_down(s1, off, 64);
        if (lane + off < 64) { s0 += u0; s1 += u1; }
    }
    if (lane == 0) { scr[wid] = s0; scr[4 + wid] = s1; }
    __syncthreads();                                   // B2
    float sb0 = 0.f, sb1 = 0.f;
    for (int w = wid + 1; w < 4; ++w) { sb0 += scr[w]; sb1 += scr[4 + w]; }
    float run0 = sb0 + s0 - fs0;
    float run1 = sb1 + s1 - fs1;
    #pragma unroll
    for (int k = 8; k >= 0; --k) {
        run0 += v0[k]; bs0[base + k] = run0;
        run1 += v1[k]; bs1[base + k] = run1;
    }
    __syncthreads();                                   // B3: suffix ready

    // phase 3: denom lookups (32 independent LDS reads) + logs
    float ls0 = 0.f, ls1 = 0.f;
    #pragma unroll
    for (int t = 0; t < 16; ++t) {
        int j = tid + t * 256;
        unsigned p = pb[t];
        float d0 = bs0[p & 0xFFFFu];
        float d1 = bs1[p >> 16];
        if (j != i0) ls0 += __logf(d0 + EPS_F);
        if (j != i1) ls1 += __logf(d1 + EPS_F);
    }
    #pragma unroll
    for (int off = 32; off > 0; off >>= 1) {
        ls0 += __shfl_down(ls0, off, 64);
        ls1 += __shfl_down(ls1, off, 64);
    }
    if (lane == 0) { scr[16 + wid] = ls0; scr[20 + wid] = ls1; }
    __syncthreads();                                   // B4
    if (tid == 0) {
        rowres[i0] = (scr[16] + scr[17] + scr[18] + scr[19]) - slo0;
        rowres[i1] = (scr[20] + scr[21] + scr[22] + scr[23]) - slo1;
    }
}

// ---------------- Kernel D: final reduce ----------------
__global__ __launch_bounds__(256) void final_kernel(
    const float* __restrict__ rowres, float* __restrict__ out)
{
    __shared__ float red[4];
    int tid = threadIdx.x;
    float s = 0.f;
    for (int i = tid; i < N_TOT; i += 256) s += rowres[i];
    #pragma unroll
    for (int off = 32; off > 0; off >>= 1)
        s += __shfl_down(s, off, 64);
    if ((tid & 63) == 0) red[tid >> 6] = s;
    __syncthreads();
    if (tid == 0) {
        double tot = (double)red[0] + red[1] + red[2] + red[3];
        out[0] = (float)(tot / ((double)N_TOT * (N_TOT - 1)));
    }
}

extern "C" void kernel_launch(void* const* d_in, const int* in_sizes, int n_in,
                              void* d_out, int out_size, void* d_ws, size_t ws_size,
                              hipStream_t stream)
{
    const float* z_i  = (const float*)d_in[0];
    const float* z_j  = (const float*)d_in[1];
    const float* ph_i = (const float*)d_in[2];
    const float* ph_j = (const float*)d_in[3];

    unsigned short* fb     = (unsigned short*)d_ws;                        // 2 MB bf16
    unsigned short* logits = fb + (size_t)N_TOT * D_DIM;                   // 32 MB bf16
    float*          rowres = (float*)(logits + (size_t)N_TOT * N_TOT);     // 16 KB

    normalize_kernel<<<N_TOT, 64, 0, stream>>>(z_i, z_j, fb);
    dim3 g(N_TOT / 128, N_TOT / 128);
    gemm_kernel<<<g, 256, 0, stream>>>(fb, logits);
    row_kernel<<<N_TOT / 2, 256, 0, stream>>>(logits, ph_i, ph_j, rowres);
    final_kernel<<<1, 256, 0, stream>>>(rowres, (float*)d_out);
}